// Round 1
// baseline (764.827 us; speedup 1.0000x reference)
//
#include <hip/hip_runtime.h>
#include <cfloat>
#include <cmath>

// Pipeline: (1) fused reflection-pad + adaptive max pool 3D -> pooled (B,S=256,C=32) in ws
//           (2) tiny attention + log_softmax -> out (B,32)
//
// Pad+pool collapses to plain max over input-coord windows:
//   H/W: [0,15],[15,31],[31,47],[47,63],[64,80],[80,96],[96,112],[112,127]
//   D:   [0,7],[7,15],[16,24],[24,31]
// Block decomposition: (b, c, d-half{0..15|16..31}, h-half{0..63|64..127}) -> 1024 blocks,
// no output cell shared across blocks (D splits at 15|16, H windows split at 63|64).

__device__ inline unsigned fkey(float f) {
    unsigned u = __float_as_uint(f);
    return (u & 0x80000000u) ? ~u : (u | 0x80000000u);   // order-preserving float->uint
}
__device__ inline float funkey(unsigned k) {
    return __uint_as_float((k & 0x80000000u) ? (k ^ 0x80000000u) : ~k);
}
__device__ inline float max4(float4 v) { return fmaxf(fmaxf(v.x, v.y), fmaxf(v.z, v.w)); }

__global__ __launch_bounds__(256) void pool_kernel(const float* __restrict__ x,
                                                   float* __restrict__ pooled) {
    const int blk = blockIdx.x;
    const int g_h = blk & 1;          // h-half: rows [0,63] or [64,127]
    const int g_d = (blk >> 1) & 1;   // d-half: planes [0,15] or [16,31]
    const int bc  = blk >> 2;         // b*32 + c
    const int t    = threadIdx.x;
    const int j    = t & 7;           // 16-col core 0..7
    const int rowg = t >> 3;          // 0..31 (two row passes -> 64 rows)

    __shared__ unsigned accK[2][4][8];          // [od_local][oh_local][ow]
    if (t < 64) ((unsigned*)accK)[t] = 0u;      // 0 < fkey(any finite float incl -FLT_MAX region we use)
    __syncthreads();

    const float* px = x + ((size_t)bc * 32 + (size_t)g_d * 16) * (128 * 128)
                        + (size_t)(g_h * 64 + rowg) * 128 + j * 16;
    const int lim = 7 + g_d;  // d-window membership threshold (dual plane: dl==lim)

    float a0m0 = -FLT_MAX, a0m1 = -FLT_MAX;   // row pass 0: od_local 0 / 1
    float a1m0 = -FLT_MAX, a1m1 = -FLT_MAX;   // row pass 1

    #pragma unroll 2
    for (int dl = 0; dl < 16; ++dl) {
        const float4* p0 = (const float4*)(px + (size_t)dl * (128 * 128));
        const float4* p1 = (const float4*)(px + (size_t)dl * (128 * 128) + 32 * 128);
        float4 u0 = p0[0], u1 = p0[1], u2 = p0[2], u3 = p0[3];
        float4 w0 = p1[0], w1 = p1[1], w2 = p1[2], w3 = p1[3];

        float cmax0 = fmaxf(fmaxf(max4(u0), max4(u1)), fmaxf(max4(u2), max4(u3)));
        float cmax1 = fmaxf(fmaxf(max4(w0), max4(w1)), fmaxf(max4(w2), max4(w3)));

        // window boundary fix-up: w1..w3 include last col of left core; w4..w6 include first col of right core
        float nl0 = __shfl_up(u3.w, 1, 8);
        float nf0 = __shfl_down(u0.x, 1, 8);
        float nl1 = __shfl_up(w3.w, 1, 8);
        float nf1 = __shfl_down(w0.x, 1, 8);
        if (j >= 1 && j <= 3) { cmax0 = fmaxf(cmax0, nl0); cmax1 = fmaxf(cmax1, nl1); }
        if (j >= 4 && j <= 6) { cmax0 = fmaxf(cmax0, nf0); cmax1 = fmaxf(cmax1, nf1); }

        const bool m0 = (dl <= lim), m1 = (dl >= lim);
        if (m0) { a0m0 = fmaxf(a0m0, cmax0); a1m0 = fmaxf(a1m0, cmax1); }
        if (m1) { a0m1 = fmaxf(a0m1, cmax0); a1m1 = fmaxf(a1m1, cmax1); }
    }

    // fold rows into (oh_local) cells; dual rows: {15,31,47} also feed oh+1, {80,96,112} also feed oh-1
    {
        const int rl0 = rowg, rl1 = 32 + rowg;      // local rows within the 64-row half
        const int ohl0 = rl0 >> 4, ohl1 = rl1 >> 4; // local oh 0..3
        unsigned k00 = fkey(a0m0), k01 = fkey(a0m1);
        unsigned k10 = fkey(a1m0), k11 = fkey(a1m1);
        atomicMax(&accK[0][ohl0][j], k00);
        atomicMax(&accK[1][ohl0][j], k01);
        atomicMax(&accK[0][ohl1][j], k10);
        atomicMax(&accK[1][ohl1][j], k11);
        if (g_h == 0) {
            if ((rl0 & 15) == 15) {                  // rows 15, 31
                atomicMax(&accK[0][ohl0 + 1][j], k00);
                atomicMax(&accK[1][ohl0 + 1][j], k01);
            }
            if ((rl1 & 15) == 15 && rl1 != 63) {     // row 47 (63 is a clean split)
                atomicMax(&accK[0][ohl1 + 1][j], k10);
                atomicMax(&accK[1][ohl1 + 1][j], k11);
            }
        } else {
            if ((rl0 & 15) == 0 && rl0 != 0) {       // global row 80
                atomicMax(&accK[0][ohl0 - 1][j], k00);
                atomicMax(&accK[1][ohl0 - 1][j], k01);
            }
            if ((rl1 & 15) == 0) {                   // global rows 96, 112
                atomicMax(&accK[0][ohl1 - 1][j], k10);
                atomicMax(&accK[1][ohl1 - 1][j], k11);
            }
        }
    }
    __syncthreads();

    if (t < 64) {
        const int odl = t >> 5, ohl = (t >> 3) & 3, ow = t & 7;
        float v = funkey(accK[odl][ohl][ow]);
        const int b = bc >> 5, c = bc & 31;
        const int s = (g_d * 2 + odl) * 64 + (g_h * 4 + ohl) * 8 + ow;
        pooled[((size_t)b * 256 + s) * 32 + c] = v;
    }
}

__global__ __launch_bounds__(256) void attn_kernel(const float* __restrict__ pooled,
                                                   const float* __restrict__ Wp,
                                                   const float* __restrict__ Wf,
                                                   const float* __restrict__ bfin,
                                                   float* __restrict__ out) {
    const int b = blockIdx.x;
    const int t = threadIdx.x;          // t == s (0..255)
    const int lane = t & 63, wave = t >> 6;
    __shared__ float sWp[1024];
    __shared__ float part[4][32];
    __shared__ float sctx[32];
    __shared__ float sw[32];
    __shared__ float red[4];

    for (int i = t; i < 1024; i += 256) sWp[i] = Wp[i];
    __syncthreads();

    float xf[32];
    #pragma unroll
    for (int c2 = 0; c2 < 32; ++c2) xf[c2] = pooled[(size_t)b * 8192 + t * 32 + c2];

    // x_proj[s][d] = sum_c xf[c] * Wp[d][c]
    float xp[32];
    #pragma unroll
    for (int d2 = 0; d2 < 32; ++d2) {
        float s = 0.f;
        #pragma unroll
        for (int c2 = 0; c2 < 32; ++c2) s += xf[c2] * sWp[d2 * 32 + c2];
        xp[d2] = s;
    }

    // context[d] = mean_s x_proj[s][d]
    #pragma unroll
    for (int d2 = 0; d2 < 32; ++d2) {
        float v = xp[d2];
        for (int off = 32; off >= 1; off >>= 1) v += __shfl_xor(v, off, 64);
        if (lane == 0) part[wave][d2] = v;
    }
    __syncthreads();
    if (t < 32) sctx[t] = (part[0][t] + part[1][t] + part[2][t] + part[3][t]) * (1.0f / 256.0f);
    __syncthreads();

    // att_logits[s] = dot(context, x_proj[s]); softmax over s
    float l = 0.f;
    #pragma unroll
    for (int c2 = 0; c2 < 32; ++c2) l += sctx[c2] * xp[c2];
    float v = l;
    for (int off = 32; off >= 1; off >>= 1) v = fmaxf(v, __shfl_xor(v, off, 64));
    if (lane == 0) red[wave] = v;
    __syncthreads();
    const float M = fmaxf(fmaxf(red[0], red[1]), fmaxf(red[2], red[3]));
    const float e = expf(l - M);
    v = e;
    for (int off = 32; off >= 1; off >>= 1) v += __shfl_xor(v, off, 64);
    __syncthreads();
    if (lane == 0) red[wave] = v;
    __syncthreads();
    const float S = red[0] + red[1] + red[2] + red[3];
    const float att = e / S;

    // weighted[c] = sum_s att[s] * x_proj[s][c]
    #pragma unroll
    for (int d2 = 0; d2 < 32; ++d2) {
        float w = att * xp[d2];
        for (int off = 32; off >= 1; off >>= 1) w += __shfl_xor(w, off, 64);
        if (lane == 0) part[wave][d2] = w;
    }
    __syncthreads();
    if (t < 32) sw[t] = part[0][t] + part[1][t] + part[2][t] + part[3][t];
    __syncthreads();

    // channel_logits = weighted @ Wf^T + bf; log_softmax over 32 channels
    if (t < 32) {
        float logit = bfin[t];
        #pragma unroll
        for (int k = 0; k < 32; ++k) logit += sw[k] * Wf[t * 32 + k];
        float m2 = logit;
        for (int off = 16; off >= 1; off >>= 1) m2 = fmaxf(m2, __shfl_xor(m2, off, 32));
        const float e2 = expf(logit - m2);
        float s2 = e2;
        for (int off = 16; off >= 1; off >>= 1) s2 += __shfl_xor(s2, off, 32);
        out[b * 32 + t] = logit - m2 - logf(s2);
    }
}

extern "C" void kernel_launch(void* const* d_in, const int* in_sizes, int n_in,
                              void* d_out, int out_size, void* d_ws, size_t ws_size,
                              hipStream_t stream) {
    const float* x  = (const float*)d_in[0];
    const float* Wp = (const float*)d_in[1];
    const float* Wf = (const float*)d_in[2];
    const float* bf = (const float*)d_in[3];
    float* out = (float*)d_out;
    float* pooled = (float*)d_ws;   // (8,256,32) fp32 = 256 KiB

    pool_kernel<<<dim3(1024), dim3(256), 0, stream>>>(x, pooled);
    attn_kernel<<<dim3(8), dim3(256), 0, stream>>>(pooled, Wp, Wf, bf, out);
}